// Round 8
// baseline (1906.908 us; speedup 1.0000x reference)
//
#include <hip/hip_runtime.h>

typedef __attribute__((ext_vector_type(8))) _Float16 f16x8;
typedef __attribute__((ext_vector_type(4))) float f32x4;
typedef __attribute__((ext_vector_type(2))) float f32x2;

#define MFMA16(A, Bv, Cv) __builtin_amdgcn_mfma_f32_16x16x32_f16(A, Bv, Cv, 0, 0, 0)

#define NB 8
#define CIN 512
#define NC 256
#define NQ 19

// workspace byte offsets
#define WS_WH 0            // 131072 halfs (w_hi, fragment-linear, scaled x32)
#define WS_WL 262144       // 131072 halfs (w_lo)
#define WS_W2T 524288      // 256x256 f32 (w2 transposed)
#define WS_BIAS 786432     // 256 f32
#define WS_M 787456        // 8*19*256 f32

// ---------------- K0: prep (fold BN scale into w, x32 scale, split fp16, w2^T, bias) ------
__global__ __launch_bounds__(256) void k_prep(
    const float* __restrict__ w1, const float* __restrict__ gamma,
    const float* __restrict__ beta, const float* __restrict__ mean,
    const float* __restrict__ var, const float* __restrict__ w2,
    char* __restrict__ ws) {
  _Float16* wh = (_Float16*)(ws + WS_WH);
  _Float16* wl = (_Float16*)(ws + WS_WL);
  float* w2t = (float*)(ws + WS_W2T);
  float* bias = (float*)(ws + WS_BIAS);
  const int bid = blockIdx.x, t = threadIdx.x;
  if (bid < 128) {
    // fragment-linear: elem e = aidx*8 + j, aidx = (kk*16 + mfq)*64 + l
    // lane l holds A[c = mfq*16 + (l&15)][k = kk*32 + (l>>4)*8 + j]
    for (int u = 0; u < 4; ++u) {
      int e = bid * 1024 + u * 256 + t;
      int j = e & 7, l6 = (e >> 3) & 63, mfq = (e >> 9) & 15, kk = e >> 13;
      int c = mfq * 16 + (l6 & 15);
      int k = kk * 32 + (l6 >> 4) * 8 + j;
      float sc = gamma[c] / sqrtf(var[c] + 1e-5f);
      float wf = w1[c * 512 + k] * sc * 32.0f;   // x32 keeps lo-part f16-normal
      _Float16 h = (_Float16)wf;
      wh[e] = h;
      wl[e] = (_Float16)(wf - (float)h);
    }
  } else if (bid < 192) {
    for (int u = 0; u < 4; ++u) {
      int e = (bid - 128) * 1024 + u * 256 + t;
      int i = e >> 8, o = e & 255;
      w2t[e] = w2[o * 256 + i];
    }
  } else {
    float sc = gamma[t] / sqrtf(var[t] + 1e-5f);
    bias[t] = beta[t] - mean[t] * sc;
  }
}

// ---------------- K1: conv1 (split-fp16 MFMA) + BN + ReLU + fused energy partials --------
// 8-phase-style schedule (T3+T4+T5): grid 512 = 8 b * 64 s-blocks of 256 sigma;
// 512 thr = 8 waves (h = ch-half, sq = sigma-quarter); wave = 128ch x 64sigma.
// Per K-step(32): P0 {ds_read nf01 | issue x(kk+2) | vmcnt(16) | 48 MFMA}
//                 P1 {ds_read nf23 | issue A(kk+1) | convert+ds_write buf^1 |
//                     lgkm(0) | s_barrier | 48 MFMA}   -- ONE barrier/step, vmcnt never 0.
// LDS: B dbuf 2 x 32KB: row sigma (256) x 128B (hi k0-31 | lo k0-31), XOR-swizzled
//      byte ^= (sigma&7)<<4 (write & read same convention -> conflict-free b128).
// kvq epilogue overlay @ w*8320 ([16][130] f32); bias @ 66560. Total 67584 B -> 2 blk/CU.
__global__ __launch_bounds__(512, 4) void k_conv1_energy(
    const float* __restrict__ x, const float* __restrict__ qx,
    const char* __restrict__ ws, float* __restrict__ part) {
  __shared__ __align__(16) char smem[67584];
  const int tid = threadIdx.x;
  const int l = tid & 63, w = tid >> 6;
  const int a = l & 15, g = l >> 4;
  const int h = w & 1, sq = w >> 1;
  const int bid = blockIdx.x;
  const int sblk = bid & 63, b = bid >> 6;
  const int s0 = sblk << 8;

  const f16x8* __restrict__ whv = (const f16x8*)(ws + WS_WH);
  const f16x8* __restrict__ wlv = (const f16x8*)(ws + WS_WL);
  {
    const float* bg = (const float*)(ws + WS_BIAS);
    if (tid < 256) ((float*)(smem + 66560))[tid] = bg[tid];
  }

  // staging: thread -> sigma row sig (wave-contiguous), k-half kh (16 k-rows)
  const int sig = tid & 255, kh = tid >> 8;
  const float* __restrict__ xb =
      x + (((size_t)(b * CIN + kh * 16)) << 14) + s0 + sig;
  const int wrow = sig * 128, wswz = (sig & 7) << 4;
  const int oh0 = (kh * 32) ^ wswz, oh1 = (kh * 32 + 16) ^ wswz;
  const int ol0 = (64 + kh * 32) ^ wswz, ol1 = (80 + kh * 32) ^ wswz;
  // fragment reads: row = sq*64 + nf*16 + a; hi @ (g*16)^swz, lo @ (64+g*16)^swz
  const int swzf = (a & 7) << 4;
  const int offH = (g * 16) ^ swzf, offL = (64 + g * 16) ^ swzf;
  const int frow = (sq * 64 + a) * 128;

  f32x4 acc[8][4];
  const f32x4 zz = {0.f, 0.f, 0.f, 0.f};
  #pragma unroll
  for (int i = 0; i < 8; ++i)
    #pragma unroll
    for (int j = 0; j < 4; ++j) acc[i][j] = zz;

#define CONVERT_WRITE(XR, BUFBASE) do {                                        \
    f16x8 hv0, hv1, lv0, lv1;                                                  \
    _Pragma("unroll") for (int j = 0; j < 8; ++j) {                            \
      float v = (XR)[j] * 32.f; _Float16 hh = (_Float16)v;                     \
      hv0[j] = hh; lv0[j] = (_Float16)(v - (float)hh); }                       \
    _Pragma("unroll") for (int j = 0; j < 8; ++j) {                            \
      float v = (XR)[8 + j] * 32.f; _Float16 hh = (_Float16)v;                 \
      hv1[j] = hh; lv1[j] = (_Float16)(v - (float)hh); }                       \
    char* wb_ = (BUFBASE) + wrow;                                              \
    *(f16x8*)(wb_ + oh0) = hv0; *(f16x8*)(wb_ + oh1) = hv1;                    \
    *(f16x8*)(wb_ + ol0) = lv0; *(f16x8*)(wb_ + ol1) = lv1;                    \
  } while (0)

#define DSREAD2(BUF, NF0, NF1, BH0, BL0, BH1, BL1)                             \
    BH0 = *(const f16x8*)((BUF) + frow + (NF0) * 2048 + offH);                 \
    BL0 = *(const f16x8*)((BUF) + frow + (NF0) * 2048 + offL);                 \
    BH1 = *(const f16x8*)((BUF) + frow + (NF1) * 2048 + offH);                 \
    BL1 = *(const f16x8*)((BUF) + frow + (NF1) * 2048 + offL);

#define MFMA24(AH, AL, BH, BL, NF)                                             \
    _Pragma("unroll") for (int mf = 0; mf < 8; ++mf) {                         \
      acc[mf][NF] = MFMA16(AH[mf], BH, acc[mf][NF]);                           \
      acc[mf][NF] = MFMA16(AL[mf], BH, acc[mf][NF]);                           \
      acc[mf][NF] = MFMA16(AH[mf], BL, acc[mf][NF]); }

#define LOADX(XR, T)                                                           \
    _Pragma("unroll") for (int j = 0; j < 16; ++j)                             \
      (XR)[j] = xb[((size_t)((T) * 32 + j)) << 14];

#define LOADA(AH, AL, T)                                                       \
    _Pragma("unroll") for (int mf = 0; mf < 8; ++mf) {                         \
      int ai = ((T) * 16 + h * 8 + mf) * 64 + l;                               \
      (AH)[mf] = whv[ai]; (AL)[mf] = wlv[ai]; }

  float xrA[16], xrB[16];
  f16x8 aAh[8], aAl[8], aBh[8], aBl[8];
  char* const buf0p = smem;
  char* const buf1p = smem + 32768;

  // ---- prologue: x(0)->xrB (convert now), x(1)->xrA, A(0)->aA ----
  LOADX(xrB, 0);
  LOADX(xrA, 1);
  LOADA(aAh, aAl, 0);
  asm volatile("s_waitcnt vmcnt(32)" ::: "memory");   // x(0) complete
  CONVERT_WRITE(xrB, buf0p);
  asm volatile("s_waitcnt lgkmcnt(0)" ::: "memory");
  __builtin_amdgcn_sched_barrier(0);
  __builtin_amdgcn_s_barrier();
  __builtin_amdgcn_sched_barrier(0);

  #pragma unroll 1
  for (int i = 0; i < 8; ++i) {
    const int k0 = 2 * i;
    f16x8 bh0, bl0, bh1, bl1;
    // ===== step k0 (even, cur buf0), P0 =====
    DSREAD2(buf0p, 0, 1, bh0, bl0, bh1, bl1);
    if (i < 7) {
      LOADX(xrB, k0 + 2);
      asm volatile("s_waitcnt vmcnt(16)" ::: "memory");  // A(k0) ready
    } else {
      asm volatile("s_waitcnt vmcnt(0)" ::: "memory");
    }
    asm volatile("s_waitcnt lgkmcnt(0)" ::: "memory");
    __builtin_amdgcn_sched_barrier(0);
    __builtin_amdgcn_s_setprio(1);
    MFMA24(aAh, aAl, bh0, bl0, 0);
    MFMA24(aAh, aAl, bh1, bl1, 1);
    __builtin_amdgcn_s_setprio(0);
    // ===== step k0, P1 =====
    DSREAD2(buf0p, 2, 3, bh0, bl0, bh1, bl1);
    LOADA(aBh, aBl, k0 + 1);
    CONVERT_WRITE(xrA, buf1p);                           // x(k0+1) -> buf1
    asm volatile("s_waitcnt lgkmcnt(0)" ::: "memory");
    __builtin_amdgcn_sched_barrier(0);
    __builtin_amdgcn_s_barrier();
    __builtin_amdgcn_sched_barrier(0);
    __builtin_amdgcn_s_setprio(1);
    MFMA24(aAh, aAl, bh0, bl0, 2);
    MFMA24(aAh, aAl, bh1, bl1, 3);
    __builtin_amdgcn_s_setprio(0);
    // ===== step k1 (odd, cur buf1), P0 =====
    DSREAD2(buf1p, 0, 1, bh0, bl0, bh1, bl1);
    if (i < 7) {
      LOADX(xrA, k0 + 3);
      asm volatile("s_waitcnt vmcnt(16)" ::: "memory");  // A(k1) ready
    } else {
      asm volatile("s_waitcnt vmcnt(0)" ::: "memory");
    }
    asm volatile("s_waitcnt lgkmcnt(0)" ::: "memory");
    __builtin_amdgcn_sched_barrier(0);
    __builtin_amdgcn_s_setprio(1);
    MFMA24(aBh, aBl, bh0, bl0, 0);
    MFMA24(aBh, aBl, bh1, bl1, 1);
    __builtin_amdgcn_s_setprio(0);
    // ===== step k1, P1 =====
    DSREAD2(buf1p, 2, 3, bh0, bl0, bh1, bl1);
    if (i < 7) {
      LOADA(aAh, aAl, k0 + 2);
      CONVERT_WRITE(xrB, buf0p);                         // x(k0+2) -> buf0
    }
    asm volatile("s_waitcnt lgkmcnt(0)" ::: "memory");
    __builtin_amdgcn_sched_barrier(0);
    if (i < 7) {
      __builtin_amdgcn_s_barrier();
      __builtin_amdgcn_sched_barrier(0);
    }
    __builtin_amdgcn_s_setprio(1);
    MFMA24(aBh, aBl, bh0, bl0, 2);
    MFMA24(aBh, aBl, bh1, bl1, 3);
    __builtin_amdgcn_s_setprio(0);
  }

  __syncthreads();  // all K-loop LDS traffic done before kvq overlay reuse

  // undo x32*x32 scaling, add BN bias, ReLU (c = h*128 + mf*16 + g*4 + r4)
  {
    const float* blds = (const float*)(smem + 66560);
    #pragma unroll
    for (int mf = 0; mf < 8; ++mf)
      #pragma unroll
      for (int r4 = 0; r4 < 4; ++r4) {
        float bi = blds[h * 128 + mf * 16 + g * 4 + r4];
        #pragma unroll
        for (int nf = 0; nf < 4; ++nf)
          acc[mf][nf][r4] = fmaxf(acc[mf][nf][r4] * (1.0f / 1024.0f) + bi, 0.f);
      }
  }

  // fused energy: E[n][c] = sum_sigma q[n][sigma]*feat[c][sigma]; per-wave kvq
  // transpose + wave-uniform q loads. All acc indices static (rule #20).
  float ea0[19], ea1[19];
  #pragma unroll
  for (int n = 0; n < 19; ++n) { ea0[n] = 0.f; ea1[n] = 0.f; }
  float* kvq = (float*)(smem + w * 8320);          // [16][130] f32 per wave
  const float* __restrict__ qb = qx + (((size_t)(b * NQ)) << 14) + s0 + (sq << 6);

  #pragma unroll
  for (int nf = 0; nf < 4; ++nf) {
    #pragma unroll
    for (int mf = 0; mf < 8; ++mf)
      *(f32x4*)&kvq[a * 130 + mf * 16 + g * 4] = acc[mf][nf];
    asm volatile("s_waitcnt lgkmcnt(0)" ::: "memory");
    __builtin_amdgcn_sched_barrier(0);
    #pragma unroll
    for (int spc = 0; spc < 4; ++spc) {
      float4 qv[19];
      #pragma unroll
      for (int n = 0; n < 19; ++n)
        qv[n] = *(const float4*)(qb + ((size_t)n << 14) + nf * 16 + spc * 4);
      #pragma unroll
      for (int sj = 0; sj < 4; ++sj) {
        float kv0 = kvq[(spc * 4 + sj) * 130 + l];
        float kv1 = kvq[(spc * 4 + sj) * 130 + 64 + l];
        #pragma unroll
        for (int n = 0; n < 19; ++n) {
          float qs = ((const float*)&qv[n])[sj];
          ea0[n] = fmaf(qs, kv0, ea0[n]);
          ea1[n] = fmaf(qs, kv1, ea1[n]);
        }
      }
    }
  }

  float* pp = part + (size_t)(bid * 4 + sq) * (NQ * 256) + h * 128 + l;
  #pragma unroll
  for (int n = 0; n < 19; ++n) {
    pp[n * 256] = ea0[n];
    pp[n * 256 + 64] = ea1[n];
  }
}

// ---------------- K2: reduce partials + softmax over c + M = attn @ w2^T ------------------
__global__ __launch_bounds__(256) void k_softmax_m(
    const float* __restrict__ part, const char* __restrict__ ws,
    float* __restrict__ Mout) {
  const int bn = blockIdx.x;
  const int b = bn / 19, n = bn % 19;
  const int t = threadIdx.x;
  const float* __restrict__ w2t = (const float*)(ws + WS_W2T);
  float e = 0.f;
  const float* pp = part + ((size_t)(b * 256) * NQ + n) * 256 + t;
  for (int sb = 0; sb < 256; ++sb)
    e += pp[(size_t)sb * (NQ * 256)];
  __shared__ float sred[4];
  __shared__ float attn_lds[256];
  float m = e;
  #pragma unroll
  for (int d = 1; d < 64; d <<= 1) m = fmaxf(m, __shfl_xor(m, d, 64));
  if ((t & 63) == 0) sred[t >> 6] = m;
  __syncthreads();
  m = fmaxf(fmaxf(sred[0], sred[1]), fmaxf(sred[2], sred[3]));
  float p = __expf(e - m);
  float s = p;
  #pragma unroll
  for (int d = 1; d < 64; d <<= 1) s += __shfl_xor(s, d, 64);
  __syncthreads();
  if ((t & 63) == 0) sred[t >> 6] = s;
  __syncthreads();
  s = sred[0] + sred[1] + sred[2] + sred[3];
  attn_lds[t] = p / s;
  __syncthreads();
  float macc = 0.f;
  #pragma unroll 8
  for (int i = 0; i < 256; ++i)
    macc = fmaf(attn_lds[i], w2t[i * 256 + t], macc);
  Mout[(size_t)bn * 256 + t] = macc;
}

// ---------------- K3: out[b,o,s] = sum_n M[b,n,o]*q[b,n,s] + b2[o] ------------------------
__global__ __launch_bounds__(256, 2) void k_out(
    const float* __restrict__ qx, const float* __restrict__ Mg,
    const float* __restrict__ b2, float* __restrict__ out) {
  const int bid = blockIdx.x;
  const int b = bid >> 6, sc = bid & 63;
  const int s0 = sc * 256;
  const int t = threadIdx.x;
  __shared__ float qlds[19 * 256];
  for (int idx = t; idx < 19 * 256; idx += 256) {
    int n = idx >> 8, s = idx & 255;
    qlds[idx] = qx[((size_t)(b * NQ + n) << 14) + s0 + s];
  }
  __syncthreads();
  const int tg = t >> 4, a2 = (t & 15) * 2;
  #pragma unroll 1
  for (int ocg = 0; ocg < 4; ++ocg) {
    float m[4][19];
    float bi[4];
    #pragma unroll
    for (int oj = 0; oj < 4; ++oj) {
      int o = (ocg * 4 + oj) * 16 + tg;
      bi[oj] = b2[o];
      #pragma unroll
      for (int n = 0; n < 19; ++n)
        m[oj][n] = Mg[((size_t)b * NQ + n) * 256 + o];
    }
    #pragma unroll 1
    for (int sp = 0; sp < 8; ++sp) {
      int s = sp * 32 + a2;
      f32x2 acc2[4];
      #pragma unroll
      for (int oj = 0; oj < 4; ++oj) { acc2[oj].x = bi[oj]; acc2[oj].y = bi[oj]; }
      #pragma unroll
      for (int n = 0; n < 19; ++n) {
        f32x2 q2 = *(const f32x2*)&qlds[n * 256 + s];
        #pragma unroll
        for (int oj = 0; oj < 4; ++oj) {
          acc2[oj].x = fmaf(m[oj][n], q2.x, acc2[oj].x);
          acc2[oj].y = fmaf(m[oj][n], q2.y, acc2[oj].y);
        }
      }
      #pragma unroll
      for (int oj = 0; oj < 4; ++oj) {
        int o = (ocg * 4 + oj) * 16 + tg;
        *(f32x2*)&out[((size_t)(b * NC + o) << 14) + s0 + s] = acc2[oj];
      }
    }
  }
}

extern "C" void kernel_launch(void* const* d_in, const int* in_sizes, int n_in,
                              void* d_out, int out_size, void* d_ws, size_t ws_size,
                              hipStream_t stream) {
  const float* x     = (const float*)d_in[0];
  const float* cx    = (const float*)d_in[1];
  const float* w1    = (const float*)d_in[2];
  const float* gamma = (const float*)d_in[3];
  const float* beta  = (const float*)d_in[4];
  const float* mean  = (const float*)d_in[5];
  const float* var   = (const float*)d_in[6];
  const float* w2    = (const float*)d_in[7];
  const float* b2    = (const float*)d_in[8];
  char* ws = (char*)d_ws;
  float* out = (float*)d_out;
  // energy partials [512 blk][4 sq][19][256] f32 (~40 MB) overlay d_out; consumed by
  // k_softmax_m before k_out overwrites the full output. Deterministic.
  float* part = (float*)d_out;
  float* Mptr = (float*)(ws + WS_M);

  k_prep<<<193, 256, 0, stream>>>(w1, gamma, beta, mean, var, w2, ws);
  k_conv1_energy<<<512, 512, 0, stream>>>(x, cx, ws, part);
  k_softmax_m<<<152, 256, 0, stream>>>(part, ws, Mptr);
  k_out<<<512, 256, 0, stream>>>(cx, Mptr, b2, out);
}

// Round 9
// 288.447 us; speedup vs baseline: 6.6109x; 6.6109x over previous
//
#include <hip/hip_runtime.h>

typedef __attribute__((ext_vector_type(8))) _Float16 f16x8;
typedef __attribute__((ext_vector_type(4))) float f32x4;
typedef __attribute__((ext_vector_type(2))) float f32x2;

#define MFMA16(A, Bv, Cv) __builtin_amdgcn_mfma_f32_16x16x32_f16(A, Bv, Cv, 0, 0, 0)

#define NB 8
#define CIN 512
#define NC 256
#define NQ 19

// workspace byte offsets
#define WS_WH 0            // 131072 halfs (w_hi, fragment-linear, scaled x32)
#define WS_WL 262144       // 131072 halfs (w_lo)
#define WS_W2T 524288      // 256x256 f32 (w2 transposed)
#define WS_BIAS 786432     // 256 f32
#define WS_M 787456        // 8*19*256 f32

// ---------------- K0: prep (fold BN scale into w, x32 scale, split fp16, w2^T, bias) ------
__global__ __launch_bounds__(256) void k_prep(
    const float* __restrict__ w1, const float* __restrict__ gamma,
    const float* __restrict__ beta, const float* __restrict__ mean,
    const float* __restrict__ var, const float* __restrict__ w2,
    char* __restrict__ ws) {
  _Float16* wh = (_Float16*)(ws + WS_WH);
  _Float16* wl = (_Float16*)(ws + WS_WL);
  float* w2t = (float*)(ws + WS_W2T);
  float* bias = (float*)(ws + WS_BIAS);
  const int bid = blockIdx.x, t = threadIdx.x;
  if (bid < 128) {
    // fragment-linear: elem e = aidx*8 + j, aidx = (kk*16 + mfq)*64 + l
    // lane l holds A[c = mfq*16 + (l&15)][k = kk*32 + (l>>4)*8 + j]
    for (int u = 0; u < 4; ++u) {
      int e = bid * 1024 + u * 256 + t;
      int j = e & 7, l6 = (e >> 3) & 63, mfq = (e >> 9) & 15, kk = e >> 13;
      int c = mfq * 16 + (l6 & 15);
      int k = kk * 32 + (l6 >> 4) * 8 + j;
      float sc = gamma[c] / sqrtf(var[c] + 1e-5f);
      float wf = w1[c * 512 + k] * sc * 32.0f;   // x32 keeps lo-part f16-normal
      _Float16 h = (_Float16)wf;
      wh[e] = h;
      wl[e] = (_Float16)(wf - (float)h);
    }
  } else if (bid < 192) {
    for (int u = 0; u < 4; ++u) {
      int e = (bid - 128) * 1024 + u * 256 + t;
      int i = e >> 8, o = e & 255;
      w2t[e] = w2[o * 256 + i];
    }
  } else {
    float sc = gamma[t] / sqrtf(var[t] + 1e-5f);
    bias[t] = beta[t] - mean[t] * sc;
  }
}

// ---------------- K1: conv1 (split-fp16 MFMA) + BN + ReLU + fused energy partials --------
// T3/T4/T5 cadence, register-budgeted (R8 retry; R8's launch_bounds(512,4) forced a
// 128-reg cap -> full scratch spill). grid 1024 = 8 b * 128 s-blocks of 128 sigma;
// 512 thr = 8 waves (cq = ch-quarter, sh = sigma-half); wave = 64ch x 64sigma -> acc 64.
// Per K-step(32): P0 {ds_read nf01 | issue x(kk+2) | vmcnt(8) | lgkm | 24 MFMA}
//                 P1 {ds_read nf23 | issue A(kk+1)->altbuf | convert+ds_write buf^1 |
//                     lgkm(0) | s_barrier | 24 MFMA}   -- 1 barrier/step, vmcnt never 0.
// LDS: B dbuf 2 x 16KB @0/@16384: row sigma(128) x 128B (hi 64B | lo 64B), XOR-swizzle
//      byte ^= (sig&7)<<4 on both write and read -> measured conflict-free (R8: 0).
// kvq epilogue overlay @ w*4352 ([16][68] f32, overlays B bufs); bias @ 34816.
__global__ __launch_bounds__(512, 2) void k_conv1_energy(
    const float* __restrict__ x, const float* __restrict__ qx,
    const char* __restrict__ ws, float* __restrict__ part) {
  __shared__ __align__(16) char smem[35840];
  const int tid = threadIdx.x;
  const int l = tid & 63, w = tid >> 6;
  const int a = l & 15, g = l >> 4;
  const int cq = w & 3, sh = w >> 2;
  const int bid = blockIdx.x;
  const int sblk = bid & 127, b = bid >> 7;
  const int s0 = sblk << 7;

  const f16x8* __restrict__ whv = (const f16x8*)(ws + WS_WH);
  const f16x8* __restrict__ wlv = (const f16x8*)(ws + WS_WL);
  {
    const float* bg = (const float*)(ws + WS_BIAS);
    if (tid < 256) ((float*)(smem + 34816))[tid] = bg[tid];
  }

  // staging: thread -> sigma row sig (0..127), k-chunk kh (8 k-rows of the 32-k step)
  const int sig = tid & 127, kh = tid >> 7;
  const float* __restrict__ xb =
      x + (((size_t)(b * CIN + kh * 8)) << 14) + s0 + sig;
  const int wrow = sig * 128, wswz = (sig & 7) << 4;
  const int oh0 = (kh * 16) ^ wswz;
  const int ol0 = (64 + kh * 16) ^ wswz;
  // fragment reads: row = sh*64 + nf*16 + a; (row&7) == (a&7)
  const int swzf = (a & 7) << 4;
  const int offH = (g * 16) ^ swzf, offL = (64 + g * 16) ^ swzf;
  const int frow = (sh * 64 + a) * 128;

  f32x4 acc[4][4];
  const f32x4 zz = {0.f, 0.f, 0.f, 0.f};
  #pragma unroll
  for (int i = 0; i < 4; ++i)
    #pragma unroll
    for (int j = 0; j < 4; ++j) acc[i][j] = zz;

#define CONVERT_WRITE(XR, BUFBASE) do {                                        \
    f16x8 hv0, lv0;                                                            \
    _Pragma("unroll") for (int j = 0; j < 8; ++j) {                            \
      float v = (XR)[j] * 32.f; _Float16 hh = (_Float16)v;                     \
      hv0[j] = hh; lv0[j] = (_Float16)(v - (float)hh); }                       \
    char* wb_ = (BUFBASE) + wrow;                                              \
    *(f16x8*)(wb_ + oh0) = hv0; *(f16x8*)(wb_ + ol0) = lv0;                    \
  } while (0)

#define DSREAD2(BUF, NF0, NF1, BH0, BL0, BH1, BL1)                             \
    BH0 = *(const f16x8*)((BUF) + frow + (NF0) * 2048 + offH);                 \
    BL0 = *(const f16x8*)((BUF) + frow + (NF0) * 2048 + offL);                 \
    BH1 = *(const f16x8*)((BUF) + frow + (NF1) * 2048 + offH);                 \
    BL1 = *(const f16x8*)((BUF) + frow + (NF1) * 2048 + offL);

#define MFMA12(AH, AL, BH, BL, NF)                                             \
    _Pragma("unroll") for (int mf = 0; mf < 4; ++mf) {                         \
      acc[mf][NF] = MFMA16(AH[mf], BH, acc[mf][NF]);                           \
      acc[mf][NF] = MFMA16(AL[mf], BH, acc[mf][NF]);                           \
      acc[mf][NF] = MFMA16(AH[mf], BL, acc[mf][NF]); }

#define LOADX(XR, T)                                                           \
    _Pragma("unroll") for (int j = 0; j < 8; ++j)                              \
      (XR)[j] = xb[((size_t)((T) * 32 + j)) << 14];

#define LOADA(AH, AL, T)                                                       \
    _Pragma("unroll") for (int mf = 0; mf < 4; ++mf) {                         \
      int ai = ((T) * 16 + cq * 4 + mf) * 64 + l;                              \
      (AH)[mf] = whv[ai]; (AL)[mf] = wlv[ai]; }

  float xrA[8], xrB[8];
  f16x8 aAh[4], aAl[4], aBh[4], aBl[4];
  char* const buf0p = smem;
  char* const buf1p = smem + 16384;

  // ---- prologue: x(0)->xrB (convert now), x(1)->xrA, A(0)->aA ----
  LOADX(xrB, 0);
  LOADX(xrA, 1);
  LOADA(aAh, aAl, 0);
  asm volatile("s_waitcnt vmcnt(16)" ::: "memory");   // x(0) complete
  CONVERT_WRITE(xrB, buf0p);
  asm volatile("s_waitcnt lgkmcnt(0)" ::: "memory");
  __builtin_amdgcn_sched_barrier(0);
  __builtin_amdgcn_s_barrier();
  __builtin_amdgcn_sched_barrier(0);

  #pragma unroll 1
  for (int i = 0; i < 8; ++i) {
    const int k0 = 2 * i;
    f16x8 bh0, bl0, bh1, bl1;
    // ===== step k0 (even, buf0, A in aA), P0 =====
    DSREAD2(buf0p, 0, 1, bh0, bl0, bh1, bl1);
    if (i < 7) {
      LOADX(xrB, k0 + 2);
      asm volatile("s_waitcnt vmcnt(8)" ::: "memory");   // x(k0+1), A(k0) done
    } else {
      asm volatile("s_waitcnt vmcnt(0)" ::: "memory");
    }
    asm volatile("s_waitcnt lgkmcnt(0)" ::: "memory");
    __builtin_amdgcn_sched_barrier(0);
    __builtin_amdgcn_s_setprio(1);
    MFMA12(aAh, aAl, bh0, bl0, 0);
    MFMA12(aAh, aAl, bh1, bl1, 1);
    __builtin_amdgcn_s_setprio(0);
    // ===== step k0, P1 =====
    DSREAD2(buf0p, 2, 3, bh0, bl0, bh1, bl1);
    LOADA(aBh, aBl, k0 + 1);
    CONVERT_WRITE(xrA, buf1p);                           // x(k0+1) -> buf1
    asm volatile("s_waitcnt lgkmcnt(0)" ::: "memory");
    __builtin_amdgcn_sched_barrier(0);
    __builtin_amdgcn_s_barrier();
    __builtin_amdgcn_sched_barrier(0);
    __builtin_amdgcn_s_setprio(1);
    MFMA12(aAh, aAl, bh0, bl0, 2);
    MFMA12(aAh, aAl, bh1, bl1, 3);
    __builtin_amdgcn_s_setprio(0);
    // ===== step k1 (odd, buf1, A in aB), P0 =====
    DSREAD2(buf1p, 0, 1, bh0, bl0, bh1, bl1);
    if (i < 7) {
      LOADX(xrA, k0 + 3);
      asm volatile("s_waitcnt vmcnt(8)" ::: "memory");   // x(k0+2), A(k1) done
    } else {
      asm volatile("s_waitcnt vmcnt(0)" ::: "memory");
    }
    asm volatile("s_waitcnt lgkmcnt(0)" ::: "memory");
    __builtin_amdgcn_sched_barrier(0);
    __builtin_amdgcn_s_setprio(1);
    MFMA12(aBh, aBl, bh0, bl0, 0);
    MFMA12(aBh, aBl, bh1, bl1, 1);
    __builtin_amdgcn_s_setprio(0);
    // ===== step k1, P1 =====
    DSREAD2(buf1p, 2, 3, bh0, bl0, bh1, bl1);
    if (i < 7) {
      LOADA(aAh, aAl, k0 + 2);
      CONVERT_WRITE(xrB, buf0p);                         // x(k0+2) -> buf0
    }
    asm volatile("s_waitcnt lgkmcnt(0)" ::: "memory");
    __builtin_amdgcn_sched_barrier(0);
    if (i < 7) {
      __builtin_amdgcn_s_barrier();
      __builtin_amdgcn_sched_barrier(0);
    }
    __builtin_amdgcn_s_setprio(1);
    MFMA12(aBh, aBl, bh0, bl0, 2);
    MFMA12(aBh, aBl, bh1, bl1, 3);
    __builtin_amdgcn_s_setprio(0);
  }

  __syncthreads();  // all K-loop LDS traffic done before kvq overlay reuse

  // undo x32*x32 scaling, add BN bias, ReLU (c = cq*64 + mf*16 + g*4 + r4)
  {
    const float* blds = (const float*)(smem + 34816);
    #pragma unroll
    for (int mf = 0; mf < 4; ++mf)
      #pragma unroll
      for (int r4 = 0; r4 < 4; ++r4) {
        float bi = blds[cq * 64 + mf * 16 + g * 4 + r4];
        #pragma unroll
        for (int nf = 0; nf < 4; ++nf)
          acc[mf][nf][r4] = fmaxf(acc[mf][nf][r4] * (1.0f / 1024.0f) + bi, 0.f);
      }
  }

  // fused energy: E[n][c] = sum_sigma q[n][sigma]*feat[c][sigma]; per-wave kvq
  // transpose + wave-uniform q loads. All acc indices static (rule #20).
  float ea[19];
  #pragma unroll
  for (int n = 0; n < 19; ++n) ea[n] = 0.f;
  float* kvq = (float*)(smem + w * 4352);          // [16][68] f32 per wave
  const float* __restrict__ qb =
      qx + (((size_t)(b * NQ)) << 14) + s0 + (sh << 6);

  #pragma unroll
  for (int nf = 0; nf < 4; ++nf) {
    #pragma unroll
    for (int mf = 0; mf < 4; ++mf)
      *(f32x4*)&kvq[a * 68 + mf * 16 + g * 4] = acc[mf][nf];
    asm volatile("s_waitcnt lgkmcnt(0)" ::: "memory");
    __builtin_amdgcn_sched_barrier(0);
    #pragma unroll
    for (int spc = 0; spc < 4; ++spc) {
      float4 qv[19];
      #pragma unroll
      for (int n = 0; n < 19; ++n)
        qv[n] = *(const float4*)(qb + ((size_t)n << 14) + nf * 16 + spc * 4);
      #pragma unroll
      for (int sj = 0; sj < 4; ++sj) {
        float kv = kvq[(spc * 4 + sj) * 68 + l];
        #pragma unroll
        for (int n = 0; n < 19; ++n)
          ea[n] = fmaf(((const float*)&qv[n])[sj], kv, ea[n]);
      }
    }
  }

  // partial slab = (b,sblk,sh); wave writes its 64-c slice
  float* pp = part + (size_t)((bid << 1) | sh) * (NQ * 256) + cq * 64 + l;
  #pragma unroll
  for (int n = 0; n < 19; ++n)
    pp[n * 256] = ea[n];
}

// ---------------- K2: reduce partials + softmax over c + M = attn @ w2^T ------------------
__global__ __launch_bounds__(256) void k_softmax_m(
    const float* __restrict__ part, const char* __restrict__ ws,
    float* __restrict__ Mout) {
  const int bn = blockIdx.x;
  const int b = bn / 19, n = bn % 19;
  const int t = threadIdx.x;
  const float* __restrict__ w2t = (const float*)(ws + WS_W2T);
  float e = 0.f;
  const float* pp = part + ((size_t)(b * 256) * NQ + n) * 256 + t;
  for (int sb = 0; sb < 256; ++sb)
    e += pp[(size_t)sb * (NQ * 256)];
  __shared__ float sred[4];
  __shared__ float attn_lds[256];
  float m = e;
  #pragma unroll
  for (int d = 1; d < 64; d <<= 1) m = fmaxf(m, __shfl_xor(m, d, 64));
  if ((t & 63) == 0) sred[t >> 6] = m;
  __syncthreads();
  m = fmaxf(fmaxf(sred[0], sred[1]), fmaxf(sred[2], sred[3]));
  float p = __expf(e - m);
  float s = p;
  #pragma unroll
  for (int d = 1; d < 64; d <<= 1) s += __shfl_xor(s, d, 64);
  __syncthreads();
  if ((t & 63) == 0) sred[t >> 6] = s;
  __syncthreads();
  s = sred[0] + sred[1] + sred[2] + sred[3];
  attn_lds[t] = p / s;
  __syncthreads();
  float macc = 0.f;
  #pragma unroll 8
  for (int i = 0; i < 256; ++i)
    macc = fmaf(attn_lds[i], w2t[i * 256 + t], macc);
  Mout[(size_t)bn * 256 + t] = macc;
}

// ---------------- K3: out[b,o,s] = sum_n M[b,n,o]*q[b,n,s] + b2[o] ------------------------
__global__ __launch_bounds__(256, 2) void k_out(
    const float* __restrict__ qx, const float* __restrict__ Mg,
    const float* __restrict__ b2, float* __restrict__ out) {
  const int bid = blockIdx.x;
  const int b = bid >> 6, sc = bid & 63;
  const int s0 = sc * 256;
  const int t = threadIdx.x;
  __shared__ float qlds[19 * 256];
  for (int idx = t; idx < 19 * 256; idx += 256) {
    int n = idx >> 8, s = idx & 255;
    qlds[idx] = qx[((size_t)(b * NQ + n) << 14) + s0 + s];
  }
  __syncthreads();
  const int tg = t >> 4, a2 = (t & 15) * 2;
  #pragma unroll 1
  for (int ocg = 0; ocg < 4; ++ocg) {
    float m[4][19];
    float bi[4];
    #pragma unroll
    for (int oj = 0; oj < 4; ++oj) {
      int o = (ocg * 4 + oj) * 16 + tg;
      bi[oj] = b2[o];
      #pragma unroll
      for (int n = 0; n < 19; ++n)
        m[oj][n] = Mg[((size_t)b * NQ + n) * 256 + o];
    }
    #pragma unroll 1
    for (int sp = 0; sp < 8; ++sp) {
      int s = sp * 32 + a2;
      f32x2 acc2[4];
      #pragma unroll
      for (int oj = 0; oj < 4; ++oj) { acc2[oj].x = bi[oj]; acc2[oj].y = bi[oj]; }
      #pragma unroll
      for (int n = 0; n < 19; ++n) {
        f32x2 q2 = *(const f32x2*)&qlds[n * 256 + s];
        #pragma unroll
        for (int oj = 0; oj < 4; ++oj) {
          acc2[oj].x = fmaf(m[oj][n], q2.x, acc2[oj].x);
          acc2[oj].y = fmaf(m[oj][n], q2.y, acc2[oj].y);
        }
      }
      #pragma unroll
      for (int oj = 0; oj < 4; ++oj) {
        int o = (ocg * 4 + oj) * 16 + tg;
        *(f32x2*)&out[((size_t)(b * NC + o) << 14) + s0 + s] = acc2[oj];
      }
    }
  }
}

extern "C" void kernel_launch(void* const* d_in, const int* in_sizes, int n_in,
                              void* d_out, int out_size, void* d_ws, size_t ws_size,
                              hipStream_t stream) {
  const float* x     = (const float*)d_in[0];
  const float* cx    = (const float*)d_in[1];
  const float* w1    = (const float*)d_in[2];
  const float* gamma = (const float*)d_in[3];
  const float* beta  = (const float*)d_in[4];
  const float* mean  = (const float*)d_in[5];
  const float* var   = (const float*)d_in[6];
  const float* w2    = (const float*)d_in[7];
  const float* b2    = (const float*)d_in[8];
  char* ws = (char*)d_ws;
  float* out = (float*)d_out;
  // energy partials [1024 blk][2 sh][19][256] f32 (~40 MB) overlay d_out; consumed by
  // k_softmax_m before k_out overwrites the full output. Deterministic.
  float* part = (float*)d_out;
  float* Mptr = (float*)(ws + WS_M);

  k_prep<<<193, 256, 0, stream>>>(w1, gamma, beta, mean, var, w2, ws);
  k_conv1_energy<<<1024, 512, 0, stream>>>(x, cx, ws, part);
  k_softmax_m<<<152, 256, 0, stream>>>(part, ws, Mptr);
  k_out<<<512, 256, 0, stream>>>(cx, Mptr, b2, out);
}

// Round 10
// 210.103 us; speedup vs baseline: 9.0761x; 1.3729x over previous
//
#include <hip/hip_runtime.h>

typedef __attribute__((ext_vector_type(8))) _Float16 f16x8;
typedef __attribute__((ext_vector_type(4))) float f32x4;
typedef __attribute__((ext_vector_type(2))) float f32x2;

#define MFMA16(A, Bv, Cv) __builtin_amdgcn_mfma_f32_16x16x32_f16(A, Bv, Cv, 0, 0, 0)

#define NB 8
#define CIN 512
#define NC 256
#define NQ 19

// workspace byte offsets
#define WS_WA 0            // 16 panels x 32KB: per k-step [hi 16KB][lo 16KB], frag-linear
#define WS_W2T 524288      // 256x256 f32 (w2 transposed)
#define WS_BIAS 786432     // 256 f32
#define WS_M 787456        // 8*19*256 f32

// ---------------- K0: prep (fold BN scale into w, x32 scale, split fp16, w2^T, bias) ------
// A panel layout: byte = kk*32768 + half*16384 + mfq*1024 + l*16 + j*2
//   lane l holds A[c = mfq*16 + (l&15)][k = kk*32 + (l>>4)*8 + j]
// Panels are LINEAR so global_load_lds (uniform LDS base + lane*16) reproduces them 1:1.
__global__ __launch_bounds__(256) void k_prep(
    const float* __restrict__ w1, const float* __restrict__ gamma,
    const float* __restrict__ beta, const float* __restrict__ mean,
    const float* __restrict__ var, const float* __restrict__ w2,
    char* __restrict__ ws) {
  _Float16* wa = (_Float16*)(ws + WS_WA);
  float* w2t = (float*)(ws + WS_W2T);
  float* bias = (float*)(ws + WS_BIAS);
  const int bid = blockIdx.x, t = threadIdx.x;
  if (bid < 128) {
    for (int u = 0; u < 8; ++u) {
      int i = bid * 2048 + u * 256 + t;        // halfword index 0..262143
      int kk = i >> 14, r = i & 16383;
      int half = r >> 13, q = r & 8191;
      int mfq = q >> 9, s = q & 511;
      int l = s >> 3, j = s & 7;
      int c = mfq * 16 + (l & 15);
      int k = kk * 32 + (l >> 4) * 8 + j;
      float sc = gamma[c] / sqrtf(var[c] + 1e-5f);
      float wf = w1[c * 512 + k] * sc * 32.0f;   // x32 keeps lo-part f16-normal
      _Float16 h = (_Float16)wf;
      wa[i] = half ? (_Float16)(wf - (float)h) : h;
    }
  } else if (bid < 192) {
    for (int u = 0; u < 4; ++u) {
      int e = (bid - 128) * 1024 + u * 256 + t;
      int i = e >> 8, o = e & 255;
      w2t[e] = w2[o * 256 + i];
    }
  } else {
    float sc = gamma[t] / sqrtf(var[t] + 1e-5f);
    bias[t] = beta[t] - mean[t] * sc;
  }
}

// ---------------- K1: conv1 (split-fp16 MFMA) + BN + ReLU + fused energy partials --------
// grid 2048 = 8 b * 256 s-blocks of 64; 256 thr = 4 waves; wave = 64ch x 64sigma.
// A panel: single LDS buffer @0 (32KB), refilled via global_load_lds DMA one step ahead
//   (zero VGPR cost). Read-before-overwrite: A-frag ds_reads + lgkm(0) + bar2, THEN DMA.
// B: reg-staged x -> split-f16 -> LDS dbuf @32768/@43008 ([64 sigma][40 halfs] hi + lo).
// x prefetch depth 2 (two 8-f32 register sets). vmcnt counted, never 0 mid-loop.
// LDS total 53248 -> 3 blocks/CU; bias read from ws in epilogue (not LDS).
__global__ __launch_bounds__(256, 3) void k_conv1_energy(
    const float* __restrict__ x, const float* __restrict__ qx,
    const char* __restrict__ ws, float* __restrict__ part) {
  __shared__ __align__(16) char smem[53248];
  const int tid = threadIdx.x;
  const int l = tid & 63, wm = tid >> 6;
  const int a = l & 15, g = l >> 4;
  const int bid = blockIdx.x;
  const int sblk = bid & 255, b = bid >> 8;
  const int s0 = sblk << 6;

  const char* __restrict__ wsA = ws + WS_WA;
  // B staging: thread -> sigma row (lane-consecutive), k-chunk kc = wm (8 k-rows)
  const int sigma = tid & 63, kc = wm;
  const float* __restrict__ xb = x + (((size_t)(b * CIN)) << 14) + s0 + sigma;

  f32x4 acc[4][4];
  const f32x4 zz = {0.f, 0.f, 0.f, 0.f};
  #pragma unroll
  for (int i = 0; i < 4; ++i)
    #pragma unroll
    for (int j = 0; j < 4; ++j) acc[i][j] = zz;

#define DMA_A(KK) do {                                                         \
    const char* gsrc_ = wsA + (KK) * 32768 + (wm * 8) * 1024 + l * 16;         \
    _Pragma("unroll") for (int ii = 0; ii < 8; ++ii)                           \
      __builtin_amdgcn_global_load_lds(                                        \
          (const unsigned int*)(gsrc_ + ii * 1024),                            \
          (unsigned int*)&smem[(wm * 8 + ii) * 1024], 16, 0, 0);               \
  } while (0)

#define LOADX(XR, T)                                                           \
    _Pragma("unroll") for (int j = 0; j < 8; ++j)                              \
      (XR)[j] = xb[((size_t)((T) * 32 + kc * 8 + j)) << 14];

#define CONVERT_WRITE(XR, WB) do {                                             \
    f16x8 hv_, lv_;                                                            \
    _Pragma("unroll") for (int j = 0; j < 8; ++j) {                            \
      float v = (XR)[j] * 32.f; _Float16 hh = (_Float16)v;                     \
      hv_[j] = hh; lv_[j] = (_Float16)(v - (float)hh); }                       \
    *(f16x8*)((WB) + sigma * 80 + kc * 16) = hv_;                              \
    *(f16x8*)((WB) + 5120 + sigma * 80 + kc * 16) = lv_;                       \
  } while (0)

#define AFRAG_READ(AH, AL)                                                     \
    _Pragma("unroll") for (int mf = 0; mf < 4; ++mf) {                         \
      (AH)[mf] = *(const f16x8*)&smem[(wm * 4 + mf) * 1024 + l * 16];          \
      (AL)[mf] = *(const f16x8*)&smem[16384 + (wm * 4 + mf) * 1024 + l * 16];  \
    }

#define MFMA_PHASE(RB, AH, AL)                                                 \
    _Pragma("unroll") for (int nf = 0; nf < 4; ++nf) {                         \
      f16x8 bh = *(const f16x8*)((RB) + (nf * 16 + a) * 80 + g * 16);          \
      f16x8 bl = *(const f16x8*)((RB) + 5120 + (nf * 16 + a) * 80 + g * 16);   \
      _Pragma("unroll") for (int mf = 0; mf < 4; ++mf) {                       \
        acc[mf][nf] = MFMA16((AH)[mf], bh, acc[mf][nf]);                       \
        acc[mf][nf] = MFMA16((AL)[mf], bh, acc[mf][nf]);                       \
        acc[mf][nf] = MFMA16((AH)[mf], bl, acc[mf][nf]);                       \
      }                                                                        \
    }

  char* const buf0 = smem + 32768;
  char* const buf1 = smem + 43008;
  float xrE[8], xrO[8];

  // ---- prologue: DMA A(0); x(0)->xrE, x(1)->xrO; convert x(0)->buf0 ----
  DMA_A(0);
  LOADX(xrE, 0);
  LOADX(xrO, 1);
  asm volatile("s_waitcnt vmcnt(8)" ::: "memory");   // A(0) landed, x(0) done
  CONVERT_WRITE(xrE, buf0);
  asm volatile("s_waitcnt lgkmcnt(0)" ::: "memory");
  __builtin_amdgcn_sched_barrier(0);
  __builtin_amdgcn_s_barrier();
  __builtin_amdgcn_sched_barrier(0);

  #pragma unroll 1
  for (int i = 0; i < 8; ++i) {
    f16x8 ah[4], al[4];
    // ================= step k0 = 2i (reads buf0, writes buf1) =================
    AFRAG_READ(ah, al);
    asm volatile("s_waitcnt lgkmcnt(0)" ::: "memory");   // A(k0) frags in regs
    __builtin_amdgcn_sched_barrier(0);
    __builtin_amdgcn_s_barrier();                        // bar2: all waves read A
    __builtin_amdgcn_sched_barrier(0);
    DMA_A(2 * i + 1);                                    // A(k0+1) -> ldsA (async)
    if (i < 7) {
      LOADX(xrE, 2 * i + 2);                             // x(k0+2)
      asm volatile("s_waitcnt vmcnt(16)" ::: "memory");  // x(k0+1) ready
    } else {
      asm volatile("s_waitcnt vmcnt(8)" ::: "memory");   // x(15) ready (A15 flying)
    }
    __builtin_amdgcn_sched_barrier(0);
    CONVERT_WRITE(xrO, buf1);                            // x(k0+1) -> buf1
    __builtin_amdgcn_s_setprio(1);
    MFMA_PHASE(buf0, ah, al);
    __builtin_amdgcn_s_setprio(0);
    if (i < 7) {
      asm volatile("s_waitcnt vmcnt(8) lgkmcnt(0)" ::: "memory");  // A(k0+1) landed
    } else {
      asm volatile("s_waitcnt vmcnt(0) lgkmcnt(0)" ::: "memory");
    }
    __builtin_amdgcn_sched_barrier(0);
    __builtin_amdgcn_s_barrier();                        // bar1 -> step k1
    __builtin_amdgcn_sched_barrier(0);
    // ================= step k1 = 2i+1 (reads buf1, writes buf0) ===============
    AFRAG_READ(ah, al);
    asm volatile("s_waitcnt lgkmcnt(0)" ::: "memory");
    __builtin_amdgcn_sched_barrier(0);
    if (i < 7) {
      __builtin_amdgcn_s_barrier();                      // bar2
      __builtin_amdgcn_sched_barrier(0);
      DMA_A(2 * i + 2);                                  // A(k1+1)
      LOADX(xrO, 2 * i + 3);                             // x(k1+2)
      asm volatile("s_waitcnt vmcnt(16)" ::: "memory");  // x(k1+1) ready
      __builtin_amdgcn_sched_barrier(0);
      CONVERT_WRITE(xrE, buf0);                          // x(k1+1) -> buf0
    }
    __builtin_amdgcn_s_setprio(1);
    MFMA_PHASE(buf1, ah, al);
    __builtin_amdgcn_s_setprio(0);
    if (i < 7) {
      asm volatile("s_waitcnt vmcnt(8) lgkmcnt(0)" ::: "memory");  // A(k1+1) landed
      __builtin_amdgcn_sched_barrier(0);
      __builtin_amdgcn_s_barrier();                      // bar1 -> next pair
      __builtin_amdgcn_sched_barrier(0);
    }
  }

  __syncthreads();  // drain everything; LDS reused by epilogue kvq overlay

  // undo x32*x32 scaling, add BN bias (from ws, L2-hot), ReLU
  {
    const float* __restrict__ biasg = (const float*)(ws + WS_BIAS);
    #pragma unroll
    for (int mf = 0; mf < 4; ++mf) {
      const float4 bq = *(const float4*)(biasg + wm * 64 + mf * 16 + g * 4);
      #pragma unroll
      for (int r4 = 0; r4 < 4; ++r4) {
        float bi = ((const float*)&bq)[r4];
        #pragma unroll
        for (int nf = 0; nf < 4; ++nf)
          acc[mf][nf][r4] = fmaxf(acc[mf][nf][r4] * (1.0f / 1024.0f) + bi, 0.f);
      }
    }
  }

  // fused energy: E[n][c] = sum_sigma q[n][sigma]*feat[c][sigma]; per-wave kvq
  // transpose + wave-uniform q loads. All acc indices static (rule #20).
  float ea[19];
  #pragma unroll
  for (int n = 0; n < 19; ++n) ea[n] = 0.f;
  float* kvq = (float*)(smem + wm * 4352);        // [16][68] f32, overlays A region
  const float* __restrict__ qb = qx + (((size_t)(b * NQ)) << 14) + s0;

  #pragma unroll
  for (int nf = 0; nf < 4; ++nf) {
    #pragma unroll
    for (int mf = 0; mf < 4; ++mf)
      *(f32x4*)&kvq[a * 68 + mf * 16 + g * 4] = acc[mf][nf];
    asm volatile("s_waitcnt lgkmcnt(0)" ::: "memory");
    __builtin_amdgcn_sched_barrier(0);
    #pragma unroll
    for (int spc = 0; spc < 4; ++spc) {
      float4 qv[19];
      #pragma unroll
      for (int n = 0; n < 19; ++n)
        qv[n] = *(const float4*)(qb + ((size_t)n << 14) + nf * 16 + spc * 4);
      #pragma unroll
      for (int sj = 0; sj < 4; ++sj) {
        float kv = kvq[(spc * 4 + sj) * 68 + l];
        #pragma unroll
        for (int n = 0; n < 19; ++n)
          ea[n] = fmaf(((const float*)&qv[n])[sj], kv, ea[n]);
      }
    }
  }

  float* pp = part + (size_t)bid * (NQ * 256) + wm * 64 + l;
  #pragma unroll
  for (int n = 0; n < 19; ++n)
    pp[n * 256] = ea[n];
}

// ---------------- K2: reduce partials + softmax over c + M = attn @ w2^T ------------------
__global__ __launch_bounds__(256) void k_softmax_m(
    const float* __restrict__ part, const char* __restrict__ ws,
    float* __restrict__ Mout) {
  const int bn = blockIdx.x;
  const int b = bn / 19, n = bn % 19;
  const int t = threadIdx.x;
  const float* __restrict__ w2t = (const float*)(ws + WS_W2T);
  float e = 0.f;
  const float* pp = part + ((size_t)(b * 256) * NQ + n) * 256 + t;
  for (int sb = 0; sb < 256; ++sb)
    e += pp[(size_t)sb * (NQ * 256)];
  __shared__ float sred[4];
  __shared__ float attn_lds[256];
  float m = e;
  #pragma unroll
  for (int d = 1; d < 64; d <<= 1) m = fmaxf(m, __shfl_xor(m, d, 64));
  if ((t & 63) == 0) sred[t >> 6] = m;
  __syncthreads();
  m = fmaxf(fmaxf(sred[0], sred[1]), fmaxf(sred[2], sred[3]));
  float p = __expf(e - m);
  float s = p;
  #pragma unroll
  for (int d = 1; d < 64; d <<= 1) s += __shfl_xor(s, d, 64);
  __syncthreads();
  if ((t & 63) == 0) sred[t >> 6] = s;
  __syncthreads();
  s = sred[0] + sred[1] + sred[2] + sred[3];
  attn_lds[t] = p / s;
  __syncthreads();
  float macc = 0.f;
  #pragma unroll 8
  for (int i = 0; i < 256; ++i)
    macc = fmaf(attn_lds[i], w2t[i * 256 + t], macc);
  Mout[(size_t)bn * 256 + t] = macc;
}

// ---------------- K3: out[b,o,s] = sum_n M[b,n,o]*q[b,n,s] + b2[o] ------------------------
__global__ __launch_bounds__(256, 2) void k_out(
    const float* __restrict__ qx, const float* __restrict__ Mg,
    const float* __restrict__ b2, float* __restrict__ out) {
  const int bid = blockIdx.x;
  const int b = bid >> 6, sc = bid & 63;
  const int s0 = sc * 256;
  const int t = threadIdx.x;
  __shared__ float qlds[19 * 256];
  for (int idx = t; idx < 19 * 256; idx += 256) {
    int n = idx >> 8, s = idx & 255;
    qlds[idx] = qx[((size_t)(b * NQ + n) << 14) + s0 + s];
  }
  __syncthreads();
  const int tg = t >> 4, a2 = (t & 15) * 2;
  #pragma unroll 1
  for (int ocg = 0; ocg < 4; ++ocg) {
    float m[4][19];
    float bi[4];
    #pragma unroll
    for (int oj = 0; oj < 4; ++oj) {
      int o = (ocg * 4 + oj) * 16 + tg;
      bi[oj] = b2[o];
      #pragma unroll
      for (int n = 0; n < 19; ++n)
        m[oj][n] = Mg[((size_t)b * NQ + n) * 256 + o];
    }
    #pragma unroll 1
    for (int sp = 0; sp < 8; ++sp) {
      int s = sp * 32 + a2;
      f32x2 acc2[4];
      #pragma unroll
      for (int oj = 0; oj < 4; ++oj) { acc2[oj].x = bi[oj]; acc2[oj].y = bi[oj]; }
      #pragma unroll
      for (int n = 0; n < 19; ++n) {
        f32x2 q2 = *(const f32x2*)&qlds[n * 256 + s];
        #pragma unroll
        for (int oj = 0; oj < 4; ++oj) {
          acc2[oj].x = fmaf(m[oj][n], q2.x, acc2[oj].x);
          acc2[oj].y = fmaf(m[oj][n], q2.y, acc2[oj].y);
        }
      }
      #pragma unroll
      for (int oj = 0; oj < 4; ++oj) {
        int o = (ocg * 4 + oj) * 16 + tg;
        *(f32x2*)&out[((size_t)(b * NC + o) << 14) + s0 + s] = acc2[oj];
      }
    }
  }
}

extern "C" void kernel_launch(void* const* d_in, const int* in_sizes, int n_in,
                              void* d_out, int out_size, void* d_ws, size_t ws_size,
                              hipStream_t stream) {
  const float* x     = (const float*)d_in[0];
  const float* cx    = (const float*)d_in[1];
  const float* w1    = (const float*)d_in[2];
  const float* gamma = (const float*)d_in[3];
  const float* beta  = (const float*)d_in[4];
  const float* mean  = (const float*)d_in[5];
  const float* var   = (const float*)d_in[6];
  const float* w2    = (const float*)d_in[7];
  const float* b2    = (const float*)d_in[8];
  char* ws = (char*)d_ws;
  float* out = (float*)d_out;
  // energy partials [2048 tiles][19][256] f32 (~40 MB) overlay d_out; consumed by
  // k_softmax_m before k_out overwrites the full output. Deterministic.
  float* part = (float*)d_out;
  float* Mptr = (float*)(ws + WS_M);

  k_prep<<<193, 256, 0, stream>>>(w1, gamma, beta, mean, var, w2, ws);
  k_conv1_energy<<<2048, 256, 0, stream>>>(x, cx, ws, part);
  k_softmax_m<<<152, 256, 0, stream>>>(part, ws, Mptr);
  k_out<<<512, 256, 0, stream>>>(cx, Mptr, b2, out);
}